// Round 1
// baseline (505.311 us; speedup 1.0000x reference)
//
#include <hip/hip_runtime.h>
#include <cstdint>
#include <cstddef>

// Problem constants (from reference): B=8, T=4096, D=512, H=512
constexpr int Bb = 8, Tt = 4096, Dd = 512, Hh = 512;
constexpr int Mm = Bb * Tt;          // 32768 rows
constexpr int CHUNKS = 128;          // scan chunks per sequence
constexpr int CLEN = Tt / CHUNKS;    // 32 steps per chunk

#define BM 64
#define BN 64
#define BK 32
#define LDSROW (BM + 4)              // pad 4 floats: keeps 16B alignment, breaks 8-way store conflict

// Fused dual-GEMM + gate activations.
// k  = x @ Wz^T + bz ; ph = x @ Wh^T + bh
// a  = sigmoid(-k)  -> a_out (ws)
// v  = sigmoid(k) * g(ph) -> v_out (d_out, scratch until scan_apply overwrites)
__global__ __launch_bounds__(256) void gemm_act(
    const float* __restrict__ x, const float* __restrict__ Wz, const float* __restrict__ bz,
    const float* __restrict__ Wh, const float* __restrict__ bh,
    float* __restrict__ a_out, float* __restrict__ v_out) {
  __shared__ float As [BK][LDSROW];
  __shared__ float Bzs[BK][LDSROW];
  __shared__ float Bhs[BK][LDSROW];

  const int tid = threadIdx.x;
  const int bm = blockIdx.x, bn = blockIdx.y;
  const int row0 = bm * BM, col0 = bn * BN;
  const int tm = (tid >> 4) * 4;     // output row offset within tile
  const int tn = (tid & 15) * 4;     // output col offset within tile
  const int lrow = tid >> 3;         // 0..31 staging row
  const int lk   = (tid & 7) * 4;    // 0..28 staging k offset (float4)

  float accK[4][4] = {{0.f}};
  float accH[4][4] = {{0.f}};

  for (int k0 = 0; k0 < Dd; k0 += BK) {
    float4 ax0 = *(const float4*)(x  + (size_t)(row0 + lrow)      * Dd + k0 + lk);
    float4 ax1 = *(const float4*)(x  + (size_t)(row0 + lrow + 32) * Dd + k0 + lk);
    float4 bz0 = *(const float4*)(Wz + (size_t)(col0 + lrow)      * Dd + k0 + lk);
    float4 bz1 = *(const float4*)(Wz + (size_t)(col0 + lrow + 32) * Dd + k0 + lk);
    float4 bh0 = *(const float4*)(Wh + (size_t)(col0 + lrow)      * Dd + k0 + lk);
    float4 bh1 = *(const float4*)(Wh + (size_t)(col0 + lrow + 32) * Dd + k0 + lk);

    __syncthreads();
    // transposed stores so the inner loop does contiguous ds_read_b128
    As [lk+0][lrow] = ax0.x; As [lk+1][lrow] = ax0.y; As [lk+2][lrow] = ax0.z; As [lk+3][lrow] = ax0.w;
    As [lk+0][lrow+32] = ax1.x; As [lk+1][lrow+32] = ax1.y; As [lk+2][lrow+32] = ax1.z; As [lk+3][lrow+32] = ax1.w;
    Bzs[lk+0][lrow] = bz0.x; Bzs[lk+1][lrow] = bz0.y; Bzs[lk+2][lrow] = bz0.z; Bzs[lk+3][lrow] = bz0.w;
    Bzs[lk+0][lrow+32] = bz1.x; Bzs[lk+1][lrow+32] = bz1.y; Bzs[lk+2][lrow+32] = bz1.z; Bzs[lk+3][lrow+32] = bz1.w;
    Bhs[lk+0][lrow] = bh0.x; Bhs[lk+1][lrow] = bh0.y; Bhs[lk+2][lrow] = bh0.z; Bhs[lk+3][lrow] = bh0.w;
    Bhs[lk+0][lrow+32] = bh1.x; Bhs[lk+1][lrow+32] = bh1.y; Bhs[lk+2][lrow+32] = bh1.z; Bhs[lk+3][lrow+32] = bh1.w;
    __syncthreads();

#pragma unroll
    for (int kk = 0; kk < BK; ++kk) {
      float4 av  = *(const float4*)&As [kk][tm];
      float4 bzv = *(const float4*)&Bzs[kk][tn];
      float4 bhv = *(const float4*)&Bhs[kk][tn];
      float aa[4] = {av.x, av.y, av.z, av.w};
      float zz[4] = {bzv.x, bzv.y, bzv.z, bzv.w};
      float hh[4] = {bhv.x, bhv.y, bhv.z, bhv.w};
#pragma unroll
      for (int i = 0; i < 4; ++i) {
#pragma unroll
        for (int j = 0; j < 4; ++j) {
          accK[i][j] = fmaf(aa[i], zz[j], accK[i][j]);
          accH[i][j] = fmaf(aa[i], hh[j], accH[i][j]);
        }
      }
    }
  }

  // epilogue: biases + activations + stores
  float bzv[4], bhv[4];
#pragma unroll
  for (int j = 0; j < 4; ++j) {
    bzv[j] = bz[col0 + tn + j];
    bhv[j] = bh[col0 + tn + j];
  }
#pragma unroll
  for (int i = 0; i < 4; ++i) {
    float4 av, vv;
    float* ap = (float*)&av;
    float* vp = (float*)&vv;
#pragma unroll
    for (int j = 0; j < 4; ++j) {
      float kv = accK[i][j] + bzv[j];
      float ph = accH[i][j] + bhv[j];
      float a   = 1.f / (1.f + expf(kv));    // sigmoid(-k) = 1 - z
      float sig = 1.f / (1.f + expf(-kv));   // z
      float gv  = (ph >= 0.f) ? (ph + 0.5f) : 1.f / (1.f + expf(-ph));
      ap[j] = a;
      vp[j] = sig * gv;
    }
    size_t o = (size_t)(row0 + tm + i) * Hh + col0 + tn;
    *(float4*)(a_out + o) = av;
    *(float4*)(v_out + o) = vv;
  }
}

// Pass A: per-chunk aggregates. block = (b,c), thread = h.
__global__ __launch_bounds__(512) void scan_chunk(
    const float* __restrict__ a, const float* __restrict__ v,
    float* __restrict__ aggA, float* __restrict__ aggH) {
  const int h = threadIdx.x;
  const int bc = blockIdx.x;
  const int b = bc / CHUNKS, c = bc % CHUNKS;
  size_t base = ((size_t)b * Tt + (size_t)c * CLEN) * Hh + h;
  float Ap = 1.f, Hend = 0.f;
#pragma unroll
  for (int i = 0; i < CLEN; ++i) {
    float av = a[base + (size_t)i * Hh];
    float vv = v[base + (size_t)i * Hh];
    Hend = fmaf(av, Hend, vv);
    Ap *= av;
  }
  aggA[(size_t)bc * Hh + h] = Ap;
  aggH[(size_t)bc * Hh + h] = Hend;
}

// Pass B: sequential carry across chunks. 4096 independent (b,h) channels.
__global__ __launch_bounds__(256) void scan_carry(
    const float* __restrict__ aggA, const float* __restrict__ aggH,
    const float* __restrict__ h0, float* __restrict__ carry) {
  const int gid = blockIdx.x * 256 + threadIdx.x;  // 0..B*H-1
  const int b = gid >> 9, h = gid & 511;
  float hv = h0[gid];
  float cur = (hv >= 0.f) ? (hv + 0.5f) : 1.f / (1.f + expf(-hv));  // g(h0)
  for (int c = 0; c < CHUNKS; ++c) {
    size_t idx = ((size_t)b * CHUNKS + c) * Hh + h;
    carry[idx] = cur;
    cur = fmaf(aggA[idx], cur, aggH[idx]);
  }
}

// Pass C: apply carry-in, rewrite v (in d_out) with final h in place.
__global__ __launch_bounds__(512) void scan_apply(
    const float* __restrict__ a, const float* __restrict__ carry,
    float* __restrict__ out) {
  const int h = threadIdx.x;
  const int bc = blockIdx.x;
  const int b = bc / CHUNKS, c = bc % CHUNKS;
  float hprev = carry[(size_t)bc * Hh + h];
  size_t base = ((size_t)b * Tt + (size_t)c * CLEN) * Hh + h;
#pragma unroll
  for (int i = 0; i < CLEN; ++i) {
    size_t idx = base + (size_t)i * Hh;
    float av = a[idx];
    float vv = out[idx];
    hprev = fmaf(av, hprev, vv);
    out[idx] = hprev;
  }
}

extern "C" void kernel_launch(void* const* d_in, const int* in_sizes, int n_in,
                              void* d_out, int out_size, void* d_ws, size_t ws_size,
                              hipStream_t stream) {
  const float* x  = (const float*)d_in[0];
  const float* h0 = (const float*)d_in[1];
  const float* Wz = (const float*)d_in[2];
  const float* bz = (const float*)d_in[3];
  const float* Wh = (const float*)d_in[4];
  const float* bh = (const float*)d_in[5];
  float* out = (float*)d_out;

  float* ws_a  = (float*)d_ws;                            // M*H floats = 64 MB
  float* aggA  = ws_a + (size_t)Mm * Hh;                  // B*CHUNKS*H
  float* aggH  = aggA + (size_t)Bb * CHUNKS * Hh;
  float* carry = aggH + (size_t)Bb * CHUNKS * Hh;

  dim3 g1(Mm / BM, Hh / BN);
  gemm_act<<<g1, 256, 0, stream>>>(x, Wz, bz, Wh, bh, ws_a, out);
  scan_chunk<<<Bb * CHUNKS, 512, 0, stream>>>(ws_a, out, aggA, aggH);
  scan_carry<<<(Bb * Hh) / 256, 256, 0, stream>>>(aggA, aggH, h0, carry);
  scan_apply<<<Bb * CHUNKS, 512, 0, stream>>>(ws_a, carry, out);
}

// Round 2
// 203.001 us; speedup vs baseline: 2.4892x; 2.4892x over previous
//
#include <hip/hip_runtime.h>
#include <cstdint>
#include <cstddef>

// Problem constants: B=8, T=4096, D=512, H=512
constexpr int Bb = 8, Tt = 4096, Dd = 512, Hh = 512;
constexpr int Mm = Bb * Tt;          // 32768 rows
constexpr int Nn = 1024;             // Wz (0..511) ++ Wh (512..1023)
constexpr int CHUNKS = 128;
constexpr int CLEN = Tt / CHUNKS;    // 32

typedef short short8 __attribute__((ext_vector_type(8)));
typedef float f32x4 __attribute__((ext_vector_type(4)));

#define BMT 128
#define BNT 128
#define BKT 32

__device__ inline void gload_lds16(const void* g, void* lds) {
  __builtin_amdgcn_global_load_lds(
      (const __attribute__((address_space(1))) unsigned int*)g,
      (__attribute__((address_space(3))) unsigned int*)lds,
      16, 0, 0);
}

// Split Wz/Wh into bf16 hi/lo, concatenated as Bc[1024][512].
__global__ __launch_bounds__(256) void split_w(
    const float* __restrict__ Wz, const float* __restrict__ Wh,
    unsigned short* __restrict__ Bhi, unsigned short* __restrict__ Blo) {
  int i = blockIdx.x * 256 + threadIdx.x;            // float4 index, 0..131071
  const float* src = (i < 65536) ? (Wz + (size_t)i * 4)
                                 : (Wh + (size_t)(i - 65536) * 4);
  float4 w = *(const float4*)src;
  unsigned short hs[4], ls[4];
  const float* wp = (const float*)&w;
#pragma unroll
  for (int j = 0; j < 4; ++j) {
    unsigned int u = __float_as_uint(wp[j]);
    hs[j] = (unsigned short)(u >> 16);
    float lo = wp[j] - __uint_as_float(u & 0xFFFF0000u);
    ls[j] = (unsigned short)(__float_as_uint(lo) >> 16);
  }
  uint2 hv, lv;
  hv.x = (unsigned)hs[0] | ((unsigned)hs[1] << 16);
  hv.y = (unsigned)hs[2] | ((unsigned)hs[3] << 16);
  lv.x = (unsigned)ls[0] | ((unsigned)ls[1] << 16);
  lv.y = (unsigned)ls[2] | ((unsigned)ls[3] << 16);
  *(uint2*)(Bhi + (size_t)i * 4) = hv;
  *(uint2*)(Blo + (size_t)i * 4) = lv;
}

// Split-precision MFMA GEMM: P = x @ [Wz;Wh]^T + bias, raw preacts out.
// cols 0..511 -> kout (d_out), cols 512..1023 -> phout (ws).
__global__ __launch_bounds__(256) void gemm_mfma(
    const float* __restrict__ x,
    const unsigned short* __restrict__ Bhi, const unsigned short* __restrict__ Blo,
    const float* __restrict__ bz, const float* __restrict__ bh,
    float* __restrict__ kout, float* __restrict__ phout) {
  __shared__ unsigned short Ah[BMT * BKT];
  __shared__ unsigned short Al[BMT * BKT];
  __shared__ unsigned short Bh[BNT * BKT];
  __shared__ unsigned short Bl[BNT * BKT];

  const int tid = threadIdx.x;
  const int lane = tid & 63, wid = tid >> 6;
  // XCD-aware swizzle (2048 % 8 == 0, bijective): each XCD walks bm with all bn
  int swz = (blockIdx.x & 7) * 256 + (blockIdx.x >> 3);
  const int bm = swz >> 3, bn = swz & 7;
  const int row0 = bm * BMT, col0 = bn * BNT;

  const int wr = (wid >> 1) * 64, wc = (wid & 1) * 64;  // wave sub-tile origin
  const int fr = lane & 15, kg = lane >> 4;             // fragment row / k-group

  // B staging geometry: round r, wave wid covers rows n = r*64+wid*16+lane/4
  const int bn_row = wid * 16 + (lane >> 2);
  const int bk8 = (lane & 3) * 8;

  f32x4 acc[4][4];
#pragma unroll
  for (int i = 0; i < 4; ++i)
#pragma unroll
    for (int j = 0; j < 4; ++j) acc[i][j] = (f32x4)0.f;

  for (int k0 = 0; k0 < Dd; k0 += BKT) {
    // A: global -> regs (no LDS touch; overlaps previous compute tail)
    float4 av[4];
#pragma unroll
    for (int i = 0; i < 4; ++i) {
      int f = (i * 256 + tid) * 4;
      int r = f >> 5, kc = f & 31;
      av[i] = *(const float4*)(x + (size_t)(row0 + r) * Dd + k0 + kc);
    }
    __syncthreads();  // previous tile's LDS reads complete

    // B: async global->LDS, 16B/lane, wave-uniform LDS base
#pragma unroll
    for (int rnd = 0; rnd < 2; ++rnd) {
      int n = rnd * 64 + bn_row;
      size_t go = (size_t)(col0 + n) * Dd + k0 + bk8;
      int lbase = rnd * 2048 + wid * 512;  // elements
      gload_lds16(Bhi + go, &Bh[lbase]);
      gload_lds16(Blo + go, &Bl[lbase]);
    }

    // A: truncation-split to bf16 hi/lo, write to LDS
#pragma unroll
    for (int i = 0; i < 4; ++i) {
      int f = (i * 256 + tid) * 4;
      int r = f >> 5, kc = f & 31;
      unsigned short hs[4], ls[4];
      const float* ap = (const float*)&av[i];
#pragma unroll
      for (int j = 0; j < 4; ++j) {
        unsigned int u = __float_as_uint(ap[j]);
        hs[j] = (unsigned short)(u >> 16);
        float lo = ap[j] - __uint_as_float(u & 0xFFFF0000u);
        ls[j] = (unsigned short)(__float_as_uint(lo) >> 16);
      }
      uint2 hv, lv;
      hv.x = (unsigned)hs[0] | ((unsigned)hs[1] << 16);
      hv.y = (unsigned)hs[2] | ((unsigned)hs[3] << 16);
      lv.x = (unsigned)ls[0] | ((unsigned)ls[1] << 16);
      lv.y = (unsigned)ls[2] | ((unsigned)ls[3] << 16);
      *(uint2*)&Ah[r * BKT + kc] = hv;
      *(uint2*)&Al[r * BKT + kc] = lv;
    }
    __syncthreads();  // (compiler drains vmcnt+lgkm before barrier)

    // fragments: 8 contiguous bf16 along K per lane
    short8 fah[4], fal[4], fbh[4], fbl[4];
#pragma unroll
    for (int mi = 0; mi < 4; ++mi) {
      int off = (wr + mi * 16 + fr) * BKT + kg * 8;
      fah[mi] = *(const short8*)&Ah[off];
      fal[mi] = *(const short8*)&Al[off];
    }
#pragma unroll
    for (int ni = 0; ni < 4; ++ni) {
      int off = (wc + ni * 16 + fr) * BKT + kg * 8;
      fbh[ni] = *(const short8*)&Bh[off];
      fbl[ni] = *(const short8*)&Bl[off];
    }
#pragma unroll
    for (int mi = 0; mi < 4; ++mi)
#pragma unroll
      for (int ni = 0; ni < 4; ++ni) {
        acc[mi][ni] = __builtin_amdgcn_mfma_f32_16x16x32_bf16(fah[mi], fbh[ni], acc[mi][ni], 0, 0, 0);
        acc[mi][ni] = __builtin_amdgcn_mfma_f32_16x16x32_bf16(fal[mi], fbh[ni], acc[mi][ni], 0, 0, 0);
        acc[mi][ni] = __builtin_amdgcn_mfma_f32_16x16x32_bf16(fah[mi], fbl[ni], acc[mi][ni], 0, 0, 0);
      }
  }

  // Epilogue: add bias, store raw preact. C/D layout: col=lane&15, row=(lane>>4)*4+j
  const bool isK = (col0 < 512);
  const float* bias = isK ? bz : bh;
  float* outp = isK ? kout : phout;
  const int cb = isK ? col0 : col0 - 512;
#pragma unroll
  for (int ni = 0; ni < 4; ++ni) {
    int col = cb + wc + ni * 16 + fr;
    float bv = bias[col];
#pragma unroll
    for (int mi = 0; mi < 4; ++mi) {
#pragma unroll
      for (int j = 0; j < 4; ++j) {
        int row = row0 + wr + mi * 16 + kg * 4 + j;
        outp[(size_t)row * 512 + col] = acc[mi][ni][j] + bv;
      }
    }
  }
}

__device__ inline void gates(float kv, float pv, float& a, float& v) {
  a = 1.f / (1.f + expf(kv));          // sigmoid(-k)
  float z = 1.f - a;                   // sigmoid(k)
  float g = (pv >= 0.f) ? (pv + 0.5f) : 1.f / (1.f + expf(-pv));
  v = z * g;
}

// Pass A: per-chunk aggregates from raw preacts.
__global__ __launch_bounds__(512) void scan_chunk(
    const float* __restrict__ kpre, const float* __restrict__ ph,
    float* __restrict__ aggA, float* __restrict__ aggH) {
  const int h = threadIdx.x;
  const int bc = blockIdx.x;
  const int b = bc >> 7, c = bc & 127;
  size_t base = ((size_t)b * Tt + (size_t)c * CLEN) * Hh + h;
  float Ap = 1.f, He = 0.f;
#pragma unroll
  for (int i = 0; i < CLEN; ++i) {
    size_t idx = base + (size_t)i * Hh;
    float a, v;
    gates(kpre[idx], ph[idx], a, v);
    He = fmaf(a, He, v);
    Ap *= a;
  }
  aggA[(size_t)bc * Hh + h] = Ap;
  aggH[(size_t)bc * Hh + h] = He;
}

// Pass B: sequential carry across chunks (4096 independent channels).
__global__ __launch_bounds__(256) void scan_carry(
    const float* __restrict__ aggA, const float* __restrict__ aggH,
    const float* __restrict__ h0, float* __restrict__ carry) {
  const int gid = blockIdx.x * 256 + threadIdx.x;  // 0..B*H-1
  const int b = gid >> 9, h = gid & 511;
  float hv = h0[gid];
  float cur = (hv >= 0.f) ? (hv + 0.5f) : 1.f / (1.f + expf(-hv));  // g(h0)
  for (int c = 0; c < CHUNKS; ++c) {
    size_t idx = ((size_t)b * CHUNKS + c) * Hh + h;
    carry[idx] = cur;
    cur = fmaf(aggA[idx], cur, aggH[idx]);
  }
}

// Pass C: recompute gates, apply carry-in, overwrite kpre (d_out) with h.
__global__ __launch_bounds__(512) void scan_apply(
    const float* __restrict__ ph, const float* __restrict__ carry,
    float* __restrict__ out) {
  const int h = threadIdx.x;
  const int bc = blockIdx.x;
  const int b = bc >> 7, c = bc & 127;
  float hp = carry[(size_t)bc * Hh + h];
  size_t base = ((size_t)b * Tt + (size_t)c * CLEN) * Hh + h;
#pragma unroll
  for (int i = 0; i < CLEN; ++i) {
    size_t idx = base + (size_t)i * Hh;
    float a, v;
    gates(out[idx], ph[idx], a, v);
    hp = fmaf(a, hp, v);
    out[idx] = hp;
  }
}

extern "C" void kernel_launch(void* const* d_in, const int* in_sizes, int n_in,
                              void* d_out, int out_size, void* d_ws, size_t ws_size,
                              hipStream_t stream) {
  const float* x  = (const float*)d_in[0];
  const float* h0 = (const float*)d_in[1];
  const float* Wz = (const float*)d_in[2];
  const float* bz = (const float*)d_in[3];
  const float* Wh = (const float*)d_in[4];
  const float* bh = (const float*)d_in[5];
  float* out = (float*)d_out;

  char* w = (char*)d_ws;
  float* ph            = (float*)w;                     // 67,108,864 B
  unsigned short* Bhi  = (unsigned short*)(w + 67108864);  // 1 MB
  unsigned short* Blo  = (unsigned short*)(w + 68157440);  // 1 MB
  float* aggA          = (float*)(w + 69206016);        // 2 MB
  float* aggH          = (float*)(w + 71303168);        // 2 MB
  float* carry         = (float*)(w + 73400320);        // 2 MB

  split_w<<<512, 256, 0, stream>>>(Wz, Wh, Bhi, Blo);
  gemm_mfma<<<(Mm / BMT) * (Nn / BNT), 256, 0, stream>>>(x, Bhi, Blo, bz, bh, out, ph);
  scan_chunk<<<Bb * CHUNKS, 512, 0, stream>>>(out, ph, aggA, aggH);
  scan_carry<<<(Bb * Hh) / 256, 256, 0, stream>>>(aggA, aggH, h0, carry);
  scan_apply<<<Bb * CHUNKS, 512, 0, stream>>>(ph, carry, out);
}

// Round 3
// 189.454 us; speedup vs baseline: 2.6672x; 1.0715x over previous
//
#include <hip/hip_runtime.h>
#include <cstdint>
#include <cstddef>

// Problem constants: B=8, T=4096, D=512, H=512
constexpr int Bb = 8, Tt = 4096, Dd = 512, Hh = 512;
constexpr int Mm = Bb * Tt;          // 32768 rows
constexpr int Nn = 1024;             // Wz (0..511) ++ Wh (512..1023)
constexpr int CHUNKS = 128;
constexpr int CLEN = Tt / CHUNKS;    // 32

typedef short short8 __attribute__((ext_vector_type(8)));
typedef float f32x4 __attribute__((ext_vector_type(4)));

#define BMT 128
#define BNT 128
#define BKT 32

__device__ inline void gload_lds16(const void* g, void* lds) {
  __builtin_amdgcn_global_load_lds(
      (const __attribute__((address_space(1))) unsigned int*)g,
      (__attribute__((address_space(3))) unsigned int*)lds,
      16, 0, 0);
}

__device__ inline unsigned short bf16_rne(float f) {
  unsigned int u = __float_as_uint(f);
  unsigned int r = (u + 0x7FFFu + ((u >> 16) & 1u)) >> 16;
  return (unsigned short)r;
}

// Split Wz/Wh into bf16 hi/lo (hi=trunc, lo=residual RNE; hi+lo ~= W exactly
// to 2^-17 rel), concatenated as Bc[1024][512].
__global__ __launch_bounds__(256) void split_w(
    const float* __restrict__ Wz, const float* __restrict__ Wh,
    unsigned short* __restrict__ Bhi, unsigned short* __restrict__ Blo) {
  int i = blockIdx.x * 256 + threadIdx.x;            // float4 index, 0..131071
  const float* src = (i < 65536) ? (Wz + (size_t)i * 4)
                                 : (Wh + (size_t)(i - 65536) * 4);
  float4 w = *(const float4*)src;
  unsigned short hs[4], ls[4];
  const float* wp = (const float*)&w;
#pragma unroll
  for (int j = 0; j < 4; ++j) {
    unsigned int u = __float_as_uint(wp[j]);
    hs[j] = (unsigned short)(u >> 16);
    float lo = wp[j] - __uint_as_float(u & 0xFFFF0000u);
    ls[j] = bf16_rne(lo);
  }
  uint2 hv, lv;
  hv.x = (unsigned)hs[0] | ((unsigned)hs[1] << 16);
  hv.y = (unsigned)hs[2] | ((unsigned)hs[3] << 16);
  lv.x = (unsigned)ls[0] | ((unsigned)ls[1] << 16);
  lv.y = (unsigned)ls[2] | ((unsigned)ls[3] << 16);
  *(uint2*)(Bhi + (size_t)i * 4) = hv;
  *(uint2*)(Blo + (size_t)i * 4) = lv;
}

// 2-product split-precision MFMA GEMM: P = x_bf16 @ (W_hi + W_lo)^T + bias.
// cols 0..511 -> kout (d_out), cols 512..1023 -> phout (ws).
__global__ __launch_bounds__(256) void gemm_mfma(
    const float* __restrict__ x,
    const unsigned short* __restrict__ Bhi, const unsigned short* __restrict__ Blo,
    const float* __restrict__ bz, const float* __restrict__ bh,
    float* __restrict__ kout, float* __restrict__ phout) {
  __shared__ unsigned short Abf[BMT * BKT];   // 8 KB
  __shared__ unsigned short Bh [BNT * BKT];   // 8 KB
  __shared__ unsigned short Bl [BNT * BKT];   // 8 KB

  const int tid = threadIdx.x;
  const int lane = tid & 63, wid = tid >> 6;
  // XCD-aware swizzle (2048 % 8 == 0, bijective): each XCD walks bm with all bn
  int swz = (blockIdx.x & 7) * 256 + (blockIdx.x >> 3);
  const int bm = swz >> 3, bn = swz & 7;
  const int row0 = bm * BMT, col0 = bn * BNT;

  const int wr = (wid >> 1) * 64, wc = (wid & 1) * 64;  // wave sub-tile origin
  const int fr = lane & 15, kg = lane >> 4;             // fragment row / k-group

  // B staging: round r, wave wid covers rows n = r*64 + wid*16 + lane/4
  const int bn_row = wid * 16 + (lane >> 2);
  const int bk8 = (lane & 3) * 8;

  // A staging geometry (per thread, 4 float4s)
  const int akc = (tid * 4) & 31;        // k offset within tile
  const int ar0 = tid >> 3;              // row for i=0; row(i) = i*32 + ar0

  f32x4 acc[4][4];
#pragma unroll
  for (int i = 0; i < 4; ++i)
#pragma unroll
    for (int j = 0; j < 4; ++j) acc[i][j] = (f32x4)0.f;

  for (int k0 = 0; k0 < Dd; k0 += BKT) {
    // A: global -> regs (overlaps previous compute tail)
    float4 av[4];
#pragma unroll
    for (int i = 0; i < 4; ++i)
      av[i] = *(const float4*)(x + (size_t)(row0 + i * 32 + ar0) * Dd + k0 + akc);

    __syncthreads();  // previous tile's LDS reads complete

    // B: async global->LDS, 16B/lane, wave-uniform LDS base
#pragma unroll
    for (int rnd = 0; rnd < 2; ++rnd) {
      int n = rnd * 64 + bn_row;
      size_t go = (size_t)(col0 + n) * Dd + k0 + bk8;
      int lbase = rnd * 2048 + wid * 512;  // ushort elements
      gload_lds16(Bhi + go, &Bh[lbase]);
      gload_lds16(Blo + go, &Bl[lbase]);
    }

    // A: RNE to single bf16, write to LDS (8B per i)
#pragma unroll
    for (int i = 0; i < 4; ++i) {
      const float* ap = (const float*)&av[i];
      uint2 hv;
      hv.x = (unsigned)bf16_rne(ap[0]) | ((unsigned)bf16_rne(ap[1]) << 16);
      hv.y = (unsigned)bf16_rne(ap[2]) | ((unsigned)bf16_rne(ap[3]) << 16);
      *(uint2*)&Abf[(i * 32 + ar0) * BKT + akc] = hv;
    }
    __syncthreads();  // drains vmcnt (gload_lds) + lgkm (ds_write)

    // fragments: 8 contiguous bf16 along K per lane
    short8 fa[4], fbh[4], fbl[4];
#pragma unroll
    for (int mi = 0; mi < 4; ++mi)
      fa[mi] = *(const short8*)&Abf[(wr + mi * 16 + fr) * BKT + kg * 8];
#pragma unroll
    for (int ni = 0; ni < 4; ++ni) {
      int off = (wc + ni * 16 + fr) * BKT + kg * 8;
      fbh[ni] = *(const short8*)&Bh[off];
      fbl[ni] = *(const short8*)&Bl[off];
    }
#pragma unroll
    for (int mi = 0; mi < 4; ++mi)
#pragma unroll
      for (int ni = 0; ni < 4; ++ni) {
        acc[mi][ni] = __builtin_amdgcn_mfma_f32_16x16x32_bf16(fa[mi], fbh[ni], acc[mi][ni], 0, 0, 0);
        acc[mi][ni] = __builtin_amdgcn_mfma_f32_16x16x32_bf16(fa[mi], fbl[ni], acc[mi][ni], 0, 0, 0);
      }
  }

  // Epilogue: add bias, store raw preact. C/D layout: col=lane&15, row=(lane>>4)*4+j
  const bool isK = (col0 < 512);
  const float* bias = isK ? bz : bh;
  float* outp = isK ? kout : phout;
  const int cb = isK ? col0 : col0 - 512;
#pragma unroll
  for (int ni = 0; ni < 4; ++ni) {
    int col = cb + wc + ni * 16 + fr;
    float bv = bias[col];
#pragma unroll
    for (int mi = 0; mi < 4; ++mi) {
#pragma unroll
      for (int j = 0; j < 4; ++j) {
        int row = row0 + wr + mi * 16 + kg * 4 + j;
        outp[(size_t)row * 512 + col] = acc[mi][ni][j] + bv;
      }
    }
  }
}

__device__ inline void gates(float kv, float pv, float& a, float& v) {
  a = 1.f / (1.f + expf(kv));          // sigmoid(-k)
  float z = 1.f - a;                   // sigmoid(k)
  float g = (pv >= 0.f) ? (pv + 0.5f) : 1.f / (1.f + expf(-pv));
  v = z * g;
}

// Pass A: per-chunk aggregates from raw preacts.
__global__ __launch_bounds__(512) void scan_chunk(
    const float* __restrict__ kpre, const float* __restrict__ ph,
    float* __restrict__ aggA, float* __restrict__ aggH) {
  const int h = threadIdx.x;
  const int bc = blockIdx.x;
  const int b = bc >> 7, c = bc & 127;
  size_t base = ((size_t)b * Tt + (size_t)c * CLEN) * Hh + h;
  float Ap = 1.f, He = 0.f;
#pragma unroll
  for (int i = 0; i < CLEN; ++i) {
    size_t idx = base + (size_t)i * Hh;
    float a, v;
    gates(kpre[idx], ph[idx], a, v);
    He = fmaf(a, He, v);
    Ap *= a;
  }
  aggA[(size_t)bc * Hh + h] = Ap;
  aggH[(size_t)bc * Hh + h] = He;
}

// Pass B: sequential carry across chunks (4096 independent channels).
__global__ __launch_bounds__(256) void scan_carry(
    const float* __restrict__ aggA, const float* __restrict__ aggH,
    const float* __restrict__ h0, float* __restrict__ carry) {
  const int gid = blockIdx.x * 256 + threadIdx.x;  // 0..B*H-1
  const int b = gid >> 9, h = gid & 511;
  float hv = h0[gid];
  float cur = (hv >= 0.f) ? (hv + 0.5f) : 1.f / (1.f + expf(-hv));  // g(h0)
  for (int c = 0; c < CHUNKS; ++c) {
    size_t idx = ((size_t)b * CHUNKS + c) * Hh + h;
    carry[idx] = cur;
    cur = fmaf(aggA[idx], cur, aggH[idx]);
  }
}

// Pass C: recompute gates, apply carry-in, overwrite kpre (d_out) with h.
__global__ __launch_bounds__(512) void scan_apply(
    const float* __restrict__ ph, const float* __restrict__ carry,
    float* __restrict__ out) {
  const int h = threadIdx.x;
  const int bc = blockIdx.x;
  const int b = bc >> 7, c = bc & 127;
  float hp = carry[(size_t)bc * Hh + h];
  size_t base = ((size_t)b * Tt + (size_t)c * CLEN) * Hh + h;
#pragma unroll
  for (int i = 0; i < CLEN; ++i) {
    size_t idx = base + (size_t)i * Hh;
    float a, v;
    gates(out[idx], ph[idx], a, v);
    hp = fmaf(a, hp, v);
    out[idx] = hp;
  }
}

extern "C" void kernel_launch(void* const* d_in, const int* in_sizes, int n_in,
                              void* d_out, int out_size, void* d_ws, size_t ws_size,
                              hipStream_t stream) {
  const float* x  = (const float*)d_in[0];
  const float* h0 = (const float*)d_in[1];
  const float* Wz = (const float*)d_in[2];
  const float* bz = (const float*)d_in[3];
  const float* Wh = (const float*)d_in[4];
  const float* bh = (const float*)d_in[5];
  float* out = (float*)d_out;

  char* w = (char*)d_ws;
  float* ph            = (float*)w;                        // 67,108,864 B
  unsigned short* Bhi  = (unsigned short*)(w + 67108864);  // 1 MB
  unsigned short* Blo  = (unsigned short*)(w + 68157440);  // 1 MB
  float* aggA          = (float*)(w + 69206016);           // 2 MB
  float* aggH          = (float*)(w + 71303168);           // 2 MB
  float* carry         = (float*)(w + 73400320);           // 2 MB

  split_w<<<512, 256, 0, stream>>>(Wz, Wh, Bhi, Blo);
  gemm_mfma<<<(Mm / BMT) * (Nn / BNT), 256, 0, stream>>>(x, Bhi, Blo, bz, bh, out, ph);
  scan_chunk<<<Bb * CHUNKS, 512, 0, stream>>>(out, ph, aggA, aggH);
  scan_carry<<<(Bb * Hh) / 256, 256, 0, stream>>>(aggA, aggH, h0, carry);
  scan_apply<<<Bb * CHUNKS, 512, 0, stream>>>(ph, carry, out);
}

// Round 7
// 158.237 us; speedup vs baseline: 3.1934x; 1.1973x over previous
//
#include <hip/hip_runtime.h>
#include <cstdint>
#include <cstddef>

// Problem constants: B=8, T=4096, D=512, H=512
constexpr int Bb = 8, Tt = 4096, Dd = 512, Hh = 512;
constexpr int Mm = Bb * Tt;          // 32768 rows
constexpr int Nn = 1024;             // Wz (0..511) ++ Wh (512..1023)
constexpr int CHUNKS = 128;
constexpr int CLEN = Tt / CHUNKS;    // 32

typedef short short8 __attribute__((ext_vector_type(8)));
typedef float f32x4 __attribute__((ext_vector_type(4)));

#define BMT 128
#define BNT 128
#define BKT 64

__device__ inline void gload_lds16(const void* g, void* lds) {
  __builtin_amdgcn_global_load_lds(
      (const __attribute__((address_space(1))) unsigned int*)g,
      (__attribute__((address_space(3))) unsigned int*)lds,
      16, 0, 0);
}

__device__ inline unsigned short bf16_rne(float f) {
  unsigned int u = __float_as_uint(f);
  unsigned int r = (u + 0x7FFFu + ((u >> 16) & 1u)) >> 16;
  return (unsigned short)r;
}

__device__ inline float bf16_tof(unsigned short u) {
  return __uint_as_float(((unsigned int)u) << 16);
}

// W -> bf16 RNE, concatenated rows: Wc[1024][512], rows 0..511 = Wz, 512.. = Wh
__global__ __launch_bounds__(256) void prep_w(
    const float* __restrict__ Wz, const float* __restrict__ Wh,
    unsigned short* __restrict__ Wc) {
  int j = blockIdx.x * 256 + threadIdx.x;            // float4 idx, 0..131071
  const float* src = (j < 65536) ? (Wz + (size_t)j * 4)
                                 : (Wh + (size_t)(j - 65536) * 4);
  float4 w = *(const float4*)src;
  const float* wp = (const float*)&w;
  uint2 hv;
  hv.x = (unsigned)bf16_rne(wp[0]) | ((unsigned)bf16_rne(wp[1]) << 16);
  hv.y = (unsigned)bf16_rne(wp[2]) | ((unsigned)bf16_rne(wp[3]) << 16);
  *(uint2*)(Wc + (size_t)j * 4) = hv;
}

// x -> bf16 RNE (xb), only launched when ws is big enough
__global__ __launch_bounds__(256) void prep_x(
    const float* __restrict__ x, unsigned short* __restrict__ xb) {
  int i = blockIdx.x * 256 + threadIdx.x;            // float4 idx, 0..4194303
  float4 w = *(const float4*)(x + (size_t)i * 4);
  const float* wp = (const float*)&w;
  uint2 hv;
  hv.x = (unsigned)bf16_rne(wp[0]) | ((unsigned)bf16_rne(wp[1]) << 16);
  hv.y = (unsigned)bf16_rne(wp[2]) | ((unsigned)bf16_rne(wp[3]) << 16);
  *(uint2*)(xb + (size_t)i * 4) = hv;
}

// Pure bf16 MFMA GEMM: P = x_bf @ Wc^T + bias, preacts stored bf16.
// cols 0..511 -> kp, cols 512..1023 -> php.
// XB=1: A via global_load_lds from xb. XB=0: A reg-staged from fp32 x w/ cvt.
template <int XB>
__global__ __launch_bounds__(256) void gemm_mfma(
    const float* __restrict__ x, const unsigned short* __restrict__ xb,
    const unsigned short* __restrict__ Wc,
    const float* __restrict__ bz, const float* __restrict__ bh,
    unsigned short* __restrict__ kp, unsigned short* __restrict__ php) {
  __shared__ unsigned short Abf[BMT * BKT];   // 16 KB
  __shared__ unsigned short Bbf[BNT * BKT];   // 16 KB

  const int tid = threadIdx.x;
  const int lane = tid & 63, wid = tid >> 6;
  // XCD-aware bijective swizzle (2048 % 8 == 0)
  int swz = (blockIdx.x & 7) * 256 + (blockIdx.x >> 3);
  const int bm = swz >> 3, bn = swz & 7;
  const int row0 = bm * BMT, col0 = bn * BNT;

  const int wr = (wid >> 1) * 64, wc = (wid & 1) * 64;  // wave sub-tile origin
  const int fr = lane & 15, kg = lane >> 4;             // fragment row / k-group

  // gload geometry: per issue a wave covers 8 rows x 64 cols (1 KB)
  const int r8 = lane >> 3;          // 0..7 row within 8-row stripe
  const int c8 = (lane & 7) * 8;     // element col within row

  f32x4 acc[4][4];
#pragma unroll
  for (int i = 0; i < 4; ++i)
#pragma unroll
    for (int j = 0; j < 4; ++j) acc[i][j] = (f32x4)0.f;

  for (int k0 = 0; k0 < Dd; k0 += BKT) {
    if constexpr (XB) {
      __syncthreads();  // previous iter's fragment reads complete
#pragma unroll
      for (int i = 0; i < 4; ++i) {
        int rowA = wid * 32 + i * 8;   // wave-uniform stripe base
        gload_lds16(xb + (size_t)(row0 + rowA + r8) * Dd + k0 + c8, &Abf[rowA * BKT]);
        gload_lds16(Wc + (size_t)(col0 + rowA + r8) * Dd + k0 + c8, &Bbf[rowA * BKT]);
      }
      __syncthreads();  // compiler drains vmcnt before barrier
    } else {
      // A: global fp32 -> regs
      float4 av[8];
#pragma unroll
      for (int i = 0; i < 8; ++i) {
        int f = i * 256 + tid;
        av[i] = *(const float4*)(x + (size_t)(row0 + (f >> 4)) * Dd + k0 + (f & 15) * 4);
      }
      __syncthreads();
#pragma unroll
      for (int i = 0; i < 4; ++i) {
        int rowB = wid * 32 + i * 8;
        gload_lds16(Wc + (size_t)(col0 + rowB + r8) * Dd + k0 + c8, &Bbf[rowB * BKT]);
      }
#pragma unroll
      for (int i = 0; i < 8; ++i) {
        int f = i * 256 + tid;
        const float* ap = (const float*)&av[i];
        uint2 hv;
        hv.x = (unsigned)bf16_rne(ap[0]) | ((unsigned)bf16_rne(ap[1]) << 16);
        hv.y = (unsigned)bf16_rne(ap[2]) | ((unsigned)bf16_rne(ap[3]) << 16);
        *(uint2*)&Abf[(f >> 4) * BKT + (f & 15) * 4] = hv;
      }
      __syncthreads();
    }

    // fragments: 8 contiguous bf16 along K per lane; two K-halves (ks)
    short8 fa[2][4], fb[2][4];
#pragma unroll
    for (int mi = 0; mi < 4; ++mi) {
      int base = (wr + mi * 16 + fr) * BKT + kg * 8;
      fa[0][mi] = *(const short8*)&Abf[base];
      fa[1][mi] = *(const short8*)&Abf[base + 32];
    }
#pragma unroll
    for (int ni = 0; ni < 4; ++ni) {
      int base = (wc + ni * 16 + fr) * BKT + kg * 8;
      fb[0][ni] = *(const short8*)&Bbf[base];
      fb[1][ni] = *(const short8*)&Bbf[base + 32];
    }
#pragma unroll
    for (int mi = 0; mi < 4; ++mi)
#pragma unroll
      for (int ni = 0; ni < 4; ++ni)
        acc[mi][ni] = __builtin_amdgcn_mfma_f32_16x16x32_bf16(fa[0][mi], fb[0][ni], acc[mi][ni], 0, 0, 0);
#pragma unroll
    for (int mi = 0; mi < 4; ++mi)
#pragma unroll
      for (int ni = 0; ni < 4; ++ni)
        acc[mi][ni] = __builtin_amdgcn_mfma_f32_16x16x32_bf16(fa[1][mi], fb[1][ni], acc[mi][ni], 0, 0, 0);
  }

  // Epilogue: add bias, bf16 store. C/D layout: col=lane&15, row=(lane>>4)*4+j
  const bool isK = (col0 < 512);
  const float* bias = isK ? bz : bh;
  unsigned short* outp = isK ? kp : php;
  const int cb = isK ? col0 : col0 - 512;
#pragma unroll
  for (int ni = 0; ni < 4; ++ni) {
    int col = cb + wc + ni * 16 + fr;
    float bv = bias[col];
#pragma unroll
    for (int mi = 0; mi < 4; ++mi) {
#pragma unroll
      for (int j = 0; j < 4; ++j) {
        int row = row0 + wr + mi * 16 + kg * 4 + j;
        outp[(size_t)row * 512 + col] = bf16_rne(acc[mi][ni][j] + bv);
      }
    }
  }
}

__device__ inline void gates(float kv, float pv, float& a, float& v) {
  a = 1.f / (1.f + expf(kv));          // sigmoid(-k)
  float z = 1.f - a;                   // sigmoid(k)
  float g = (pv >= 0.f) ? (pv + 0.5f) : 1.f / (1.f + expf(-pv));
  v = z * g;
}

// Pass A: per-chunk aggregates from bf16 preacts.
__global__ __launch_bounds__(512) void scan_chunk(
    const unsigned short* __restrict__ kp, const unsigned short* __restrict__ php,
    float* __restrict__ aggA, float* __restrict__ aggH) {
  const int h = threadIdx.x;
  const int bc = blockIdx.x;
  const int b = bc >> 7, c = bc & 127;
  size_t base = ((size_t)b * Tt + (size_t)c * CLEN) * Hh + h;
  float Ap = 1.f, He = 0.f;
#pragma unroll
  for (int i = 0; i < CLEN; ++i) {
    size_t idx = base + (size_t)i * Hh;
    float a, v;
    gates(bf16_tof(kp[idx]), bf16_tof(php[idx]), a, v);
    He = fmaf(a, He, v);
    Ap *= a;
  }
  aggA[(size_t)bc * Hh + h] = Ap;
  aggH[(size_t)bc * Hh + h] = He;
}

// Pass B: sequential carry across chunks (4096 independent channels).
__global__ __launch_bounds__(256) void scan_carry(
    const float* __restrict__ aggA, const float* __restrict__ aggH,
    const float* __restrict__ h0, float* __restrict__ carry) {
  const int gid = blockIdx.x * 256 + threadIdx.x;  // 0..B*H-1
  const int b = gid >> 9, h = gid & 511;
  float hv = h0[gid];
  float cur = (hv >= 0.f) ? (hv + 0.5f) : 1.f / (1.f + expf(-hv));  // g(h0)
  for (int c = 0; c < CHUNKS; ++c) {
    size_t idx = ((size_t)b * CHUNKS + c) * Hh + h;
    carry[idx] = cur;
    cur = fmaf(aggA[idx], cur, aggH[idx]);
  }
}

// Pass C: recompute gates, apply carry-in, write final h (fp32) to d_out.
__global__ __launch_bounds__(512) void scan_apply(
    const unsigned short* __restrict__ kp, const unsigned short* __restrict__ php,
    const float* __restrict__ carry, float* __restrict__ out) {
  const int h = threadIdx.x;
  const int bc = blockIdx.x;
  const int b = bc >> 7, c = bc & 127;
  float hp = carry[(size_t)bc * Hh + h];
  size_t base = ((size_t)b * Tt + (size_t)c * CLEN) * Hh + h;
#pragma unroll
  for (int i = 0; i < CLEN; ++i) {
    size_t idx = base + (size_t)i * Hh;
    float a, v;
    gates(bf16_tof(kp[idx]), bf16_tof(php[idx]), a, v);
    hp = fmaf(a, hp, v);
    out[idx] = hp;
  }
}

extern "C" void kernel_launch(void* const* d_in, const int* in_sizes, int n_in,
                              void* d_out, int out_size, void* d_ws, size_t ws_size,
                              hipStream_t stream) {
  const float* x  = (const float*)d_in[0];
  const float* h0 = (const float*)d_in[1];
  const float* Wz = (const float*)d_in[2];
  const float* bz = (const float*)d_in[3];
  const float* Wh = (const float*)d_in[4];
  const float* bh = (const float*)d_in[5];
  float* out = (float*)d_out;

  char* w = (char*)d_ws;
  unsigned short* kp   = (unsigned short*)w;               // 32 MB
  unsigned short* php  = (unsigned short*)(w + 33554432);  // 32 MB
  unsigned short* Wc   = (unsigned short*)(w + 67108864);  // 1 MB
  float* aggA          = (float*)(w + 68157440);           // 2 MB
  float* aggH          = (float*)(w + 70254592);           // 2 MB
  float* carry         = (float*)(w + 72351744);           // 2 MB  (end 74448896)
  unsigned short* xb   = (unsigned short*)(w + 74448896);  // 32 MB (end 108003328)
  const bool useXB = ws_size >= 108003328ull;

  prep_w<<<512, 256, 0, stream>>>(Wz, Wh, Wc);
  if (useXB) {
    prep_x<<<16384, 256, 0, stream>>>(x, xb);
    gemm_mfma<1><<<(Mm / BMT) * (Nn / BNT), 256, 0, stream>>>(x, xb, Wc, bz, bh, kp, php);
  } else {
    gemm_mfma<0><<<(Mm / BMT) * (Nn / BNT), 256, 0, stream>>>(x, xb, Wc, bz, bh, kp, php);
  }
  scan_chunk<<<Bb * CHUNKS, 512, 0, stream>>>(kp, php, aggA, aggH);
  scan_carry<<<(Bb * Hh) / 256, 256, 0, stream>>>(aggA, aggH, h0, carry);
  scan_apply<<<Bb * CHUNKS, 512, 0, stream>>>(kp, php, carry, out);
}

// Round 8
// 147.071 us; speedup vs baseline: 3.4358x; 1.0759x over previous
//
#include <hip/hip_runtime.h>
#include <cstdint>
#include <cstddef>

// Problem constants: B=8, T=4096, D=512, H=512
constexpr int Bb = 8, Tt = 4096, Dd = 512, Hh = 512;
constexpr int Mm = Bb * Tt;          // 32768 rows
constexpr int Nn = 1024;             // Wz (0..511) ++ Wh (512..1023)
constexpr int CHUNKS = 128;
constexpr int CLEN = Tt / CHUNKS;    // 32

typedef short short8 __attribute__((ext_vector_type(8)));
typedef float f32x4 __attribute__((ext_vector_type(4)));

#define BMT 128
#define BNT 128
#define BKT 64

__device__ inline void gload_lds16(const void* g, void* lds) {
  __builtin_amdgcn_global_load_lds(
      (const __attribute__((address_space(1))) unsigned int*)g,
      (__attribute__((address_space(3))) unsigned int*)lds,
      16, 0, 0);
}

__device__ inline unsigned short bf16_rne(float f) {
  unsigned int u = __float_as_uint(f);
  unsigned int r = (u + 0x7FFFu + ((u >> 16) & 1u)) >> 16;
  return (unsigned short)r;
}

__device__ inline float bf16_tof(unsigned short u) {
  return __uint_as_float(((unsigned int)u) << 16);
}

__device__ inline uint2 pack4_bf16(const float* p) {
  uint2 hv;
  hv.x = (unsigned)bf16_rne(p[0]) | ((unsigned)bf16_rne(p[1]) << 16);
  hv.y = (unsigned)bf16_rne(p[2]) | ((unsigned)bf16_rne(p[3]) << 16);
  return hv;
}

// Merged prep: blocks [0,16384) convert x -> xb; blocks [16384,16896) W -> Wc.
__global__ __launch_bounds__(256) void prep_all(
    const float* __restrict__ x, const float* __restrict__ Wz,
    const float* __restrict__ Wh, unsigned short* __restrict__ xb,
    unsigned short* __restrict__ Wc) {
  int bid = blockIdx.x;
  if (bid < 16384) {
    size_t i = (size_t)bid * 256 + threadIdx.x;     // float4 idx
    float4 w = *(const float4*)(x + i * 4);
    *(uint2*)(xb + i * 4) = pack4_bf16((const float*)&w);
  } else {
    int j = (bid - 16384) * 256 + threadIdx.x;      // float4 idx, 0..131071
    const float* src = (j < 65536) ? (Wz + (size_t)j * 4)
                                   : (Wh + (size_t)(j - 65536) * 4);
    float4 w = *(const float4*)src;
    *(uint2*)(Wc + (size_t)j * 4) = pack4_bf16((const float*)&w);
  }
}

// W-only prep (fallback when ws too small for xb)
__global__ __launch_bounds__(256) void prep_w(
    const float* __restrict__ Wz, const float* __restrict__ Wh,
    unsigned short* __restrict__ Wc) {
  int j = blockIdx.x * 256 + threadIdx.x;
  const float* src = (j < 65536) ? (Wz + (size_t)j * 4)
                                 : (Wh + (size_t)(j - 65536) * 4);
  float4 w = *(const float4*)src;
  *(uint2*)(Wc + (size_t)j * 4) = pack4_bf16((const float*)&w);
}

// Pure bf16 MFMA GEMM with T2 XOR-swizzled LDS (linear dest + pre-swizzled
// global source, per rule #21). LDS tile row = 128B = 8 slots of 16B; LDS
// (r, s) holds global (r, s^(r&7)). Reads use slot^(r&7) -> 2-way max.
template <int XB>
__global__ __launch_bounds__(256) void gemm_mfma(
    const float* __restrict__ x, const unsigned short* __restrict__ xb,
    const unsigned short* __restrict__ Wc,
    const float* __restrict__ bz, const float* __restrict__ bh,
    unsigned short* __restrict__ kp, unsigned short* __restrict__ php) {
  __shared__ unsigned short Abf[BMT * BKT];   // 16 KB
  __shared__ unsigned short Bbf[BNT * BKT];   // 16 KB

  const int tid = threadIdx.x;
  const int lane = tid & 63, wid = tid >> 6;
  // XCD-aware bijective swizzle (2048 % 8 == 0)
  int swz = (blockIdx.x & 7) * 256 + (blockIdx.x >> 3);
  const int bm = swz >> 3, bn = swz & 7;
  const int row0 = bm * BMT, col0 = bn * BNT;

  const int wr = (wid >> 1) * 64, wc = (wid & 1) * 64;  // wave sub-tile origin
  const int fr = lane & 15, kg = lane >> 4;             // fragment row / k-group

  // gload geometry: per issue a wave covers 8 rows x 64 cols (1 KB), stripe
  // base is a multiple of 8 rows so r&7 == lane>>3. Pre-swizzled source slot:
  const int r8 = lane >> 3;                       // 0..7 row within stripe
  const int c8 = ((lane & 7) ^ r8) * 8;           // swizzled col slot (ushorts)

  // fragment-read swizzled slot offsets (ushorts): slot ^ (row&7), row&7 = fr&7
  const int fr7 = lane & 7;
  const int sk0 = (kg ^ fr7) * 8;                 // K-half 0 (orig slot kg)
  const int sk1 = ((kg + 4) ^ fr7) * 8;           // K-half 1 (orig slot kg+4)

  f32x4 acc[4][4];
#pragma unroll
  for (int i = 0; i < 4; ++i)
#pragma unroll
    for (int j = 0; j < 4; ++j) acc[i][j] = (f32x4)0.f;

  for (int k0 = 0; k0 < Dd; k0 += BKT) {
    if constexpr (XB) {
      __syncthreads();  // previous iter's fragment reads complete
#pragma unroll
      for (int i = 0; i < 4; ++i) {
        int rowA = wid * 32 + i * 8;   // wave-uniform stripe base (mult of 8)
        gload_lds16(xb + (size_t)(row0 + rowA + r8) * Dd + k0 + c8, &Abf[rowA * BKT]);
        gload_lds16(Wc + (size_t)(col0 + rowA + r8) * Dd + k0 + c8, &Bbf[rowA * BKT]);
      }
      __syncthreads();  // compiler drains vmcnt before barrier
    } else {
      // A: global fp32 -> regs
      float4 av[8];
#pragma unroll
      for (int i = 0; i < 8; ++i) {
        int f = i * 256 + tid;
        av[i] = *(const float4*)(x + (size_t)(row0 + (f >> 4)) * Dd + k0 + (f & 15) * 4);
      }
      __syncthreads();
#pragma unroll
      for (int i = 0; i < 4; ++i) {
        int rowB = wid * 32 + i * 8;
        gload_lds16(Wc + (size_t)(col0 + rowB + r8) * Dd + k0 + c8, &Bbf[rowB * BKT]);
      }
#pragma unroll
      for (int i = 0; i < 8; ++i) {
        int f = i * 256 + tid;
        int r = f >> 4;
        uint2 hv = pack4_bf16((const float*)&av[i]);
        // swizzled ds_write: 16B slot (f&15)>>1, half f&1
        int soff = ((((f & 15) >> 1) ^ (r & 7)) * 8) + (f & 1) * 4;
        *(uint2*)&Abf[r * BKT + soff] = hv;
      }
      __syncthreads();
    }

    // fragments: 8 contiguous bf16 along K per lane; two K-halves, swizzled
    short8 fa[2][4], fb[2][4];
#pragma unroll
    for (int mi = 0; mi < 4; ++mi) {
      int base = (wr + mi * 16 + fr) * BKT;
      fa[0][mi] = *(const short8*)&Abf[base + sk0];
      fa[1][mi] = *(const short8*)&Abf[base + sk1];
    }
#pragma unroll
    for (int ni = 0; ni < 4; ++ni) {
      int base = (wc + ni * 16 + fr) * BKT;
      fb[0][ni] = *(const short8*)&Bbf[base + sk0];
      fb[1][ni] = *(const short8*)&Bbf[base + sk1];
    }
#pragma unroll
    for (int mi = 0; mi < 4; ++mi)
#pragma unroll
      for (int ni = 0; ni < 4; ++ni)
        acc[mi][ni] = __builtin_amdgcn_mfma_f32_16x16x32_bf16(fa[0][mi], fb[0][ni], acc[mi][ni], 0, 0, 0);
#pragma unroll
    for (int mi = 0; mi < 4; ++mi)
#pragma unroll
      for (int ni = 0; ni < 4; ++ni)
        acc[mi][ni] = __builtin_amdgcn_mfma_f32_16x16x32_bf16(fa[1][mi], fb[1][ni], acc[mi][ni], 0, 0, 0);
  }

  // Epilogue: add bias, bf16 store. C/D layout: col=lane&15, row=(lane>>4)*4+j
  const bool isK = (col0 < 512);
  const float* bias = isK ? bz : bh;
  unsigned short* outp = isK ? kp : php;
  const int cb = isK ? col0 : col0 - 512;
#pragma unroll
  for (int ni = 0; ni < 4; ++ni) {
    int col = cb + wc + ni * 16 + fr;
    float bv = bias[col];
#pragma unroll
    for (int mi = 0; mi < 4; ++mi) {
#pragma unroll
      for (int j = 0; j < 4; ++j) {
        int row = row0 + wr + mi * 16 + kg * 4 + j;
        outp[(size_t)row * 512 + col] = bf16_rne(acc[mi][ni][j] + bv);
      }
    }
  }
}

__device__ inline void gates(float kv, float pv, float& a, float& v) {
  a = 1.f / (1.f + expf(kv));          // sigmoid(-k)
  float z = 1.f - a;                   // sigmoid(k)
  float g = (pv >= 0.f) ? (pv + 0.5f) : 1.f / (1.f + expf(-pv));
  v = z * g;
}

// Pass A: per-chunk aggregates from bf16 preacts.
__global__ __launch_bounds__(512) void scan_chunk(
    const unsigned short* __restrict__ kp, const unsigned short* __restrict__ php,
    float* __restrict__ aggA, float* __restrict__ aggH) {
  const int h = threadIdx.x;
  const int bc = blockIdx.x;
  const int b = bc >> 7, c = bc & 127;
  size_t base = ((size_t)b * Tt + (size_t)c * CLEN) * Hh + h;
  float Ap = 1.f, He = 0.f;
#pragma unroll
  for (int i = 0; i < CLEN; ++i) {
    size_t idx = base + (size_t)i * Hh;
    float a, v;
    gates(bf16_tof(kp[idx]), bf16_tof(php[idx]), a, v);
    He = fmaf(a, He, v);
    Ap *= a;
  }
  aggA[(size_t)bc * Hh + h] = Ap;
  aggH[(size_t)bc * Hh + h] = He;
}

// Pass B: Kogge-Stone scan over chunk aggregates (affine composition).
// Block = 256 thr = 2 channels x 128 chunks. combine(L,R)=(A_L*A_R, A_R*H_L+H_R).
__global__ __launch_bounds__(256) void scan_carry_ks(
    const float* __restrict__ aggA, const float* __restrict__ aggH,
    const float* __restrict__ h0, float* __restrict__ carry) {
  __shared__ float As[256], Hs[256];
  const int tid = threadIdx.x;
  const int c = tid & 127;
  const int gch = blockIdx.x * 2 + (tid >> 7);   // 0..B*H-1
  const int b = gch >> 9, h = gch & 511;
  size_t base = (size_t)b * CHUNKS * Hh + h;
  float A = aggA[base + (size_t)c * Hh];
  float H = aggH[base + (size_t)c * Hh];
  As[tid] = A; Hs[tid] = H;
  __syncthreads();
#pragma unroll
  for (int s = 1; s < 128; s <<= 1) {
    float Al = 1.f, Hl = 0.f;
    const bool act = (c >= s);
    if (act) { Al = As[tid - s]; Hl = Hs[tid - s]; }
    __syncthreads();
    if (act) {
      H = fmaf(A, Hl, H);   // apply cur after left-prefix
      A = A * Al;
      As[tid] = A; Hs[tid] = H;
    }
    __syncthreads();
  }
  float hv = h0[(size_t)b * Hh + h];
  float g0 = (hv >= 0.f) ? (hv + 0.5f) : 1.f / (1.f + expf(-hv));  // g(h0)
  float cr;
  if (c == 0) cr = g0;
  else cr = fmaf(As[tid - 1], g0, Hs[tid - 1]);   // exclusive prefix applied
  carry[base + (size_t)c * Hh] = cr;
}

// Pass C: recompute gates, apply carry-in, write final h (fp32) to d_out.
__global__ __launch_bounds__(512) void scan_apply(
    const unsigned short* __restrict__ kp, const unsigned short* __restrict__ php,
    const float* __restrict__ carry, float* __restrict__ out) {
  const int h = threadIdx.x;
  const int bc = blockIdx.x;
  const int b = bc >> 7, c = bc & 127;
  float hp = carry[(size_t)bc * Hh + h];
  size_t base = ((size_t)b * Tt + (size_t)c * CLEN) * Hh + h;
#pragma unroll
  for (int i = 0; i < CLEN; ++i) {
    size_t idx = base + (size_t)i * Hh;
    float a, v;
    gates(bf16_tof(kp[idx]), bf16_tof(php[idx]), a, v);
    hp = fmaf(a, hp, v);
    out[idx] = hp;
  }
}

extern "C" void kernel_launch(void* const* d_in, const int* in_sizes, int n_in,
                              void* d_out, int out_size, void* d_ws, size_t ws_size,
                              hipStream_t stream) {
  const float* x  = (const float*)d_in[0];
  const float* h0 = (const float*)d_in[1];
  const float* Wz = (const float*)d_in[2];
  const float* bz = (const float*)d_in[3];
  const float* Wh = (const float*)d_in[4];
  const float* bh = (const float*)d_in[5];
  float* out = (float*)d_out;

  char* w = (char*)d_ws;
  unsigned short* kp   = (unsigned short*)w;               // 32 MB
  unsigned short* php  = (unsigned short*)(w + 33554432);  // 32 MB
  unsigned short* Wc   = (unsigned short*)(w + 67108864);  // 1 MB
  float* aggA          = (float*)(w + 68157440);           // 2 MB
  float* aggH          = (float*)(w + 70254592);           // 2 MB
  float* carry         = (float*)(w + 72351744);           // 2 MB  (end 74448896)
  unsigned short* xb   = (unsigned short*)(w + 74448896);  // 32 MB (end 108003328)
  const bool useXB = ws_size >= 108003328ull;

  if (useXB) {
    prep_all<<<16896, 256, 0, stream>>>(x, Wz, Wh, xb, Wc);
    gemm_mfma<1><<<(Mm / BMT) * (Nn / BNT), 256, 0, stream>>>(x, xb, Wc, bz, bh, kp, php);
  } else {
    prep_w<<<512, 256, 0, stream>>>(Wz, Wh, Wc);
    gemm_mfma<0><<<(Mm / BMT) * (Nn / BNT), 256, 0, stream>>>(x, xb, Wc, bz, bh, kp, php);
  }
  scan_chunk<<<Bb * CHUNKS, 512, 0, stream>>>(kp, php, aggA, aggH);
  scan_carry_ks<<<(Bb * Hh) / 2, 256, 0, stream>>>(aggA, aggH, h0, carry);
  scan_apply<<<Bb * CHUNKS, 512, 0, stream>>>(kp, php, carry, out);
}

// Round 9
// 106.010 us; speedup vs baseline: 4.7666x; 1.3873x over previous
//
#include <hip/hip_runtime.h>
#include <hip/hip_fp16.h>
#include <cstdint>
#include <cstddef>

// Problem constants: B=8, T=4096, D=512, H=512
constexpr int Bb = 8, Tt = 4096, Dd = 512, Hh = 512;
constexpr int Mm = Bb * Tt;          // 32768 rows
constexpr int CHUNKS = 128;
constexpr int CLEN = Tt / CHUNKS;    // 32

typedef short short8 __attribute__((ext_vector_type(8)));
typedef float f32x4 __attribute__((ext_vector_type(4)));

#define BMT 128   // time-rows per block
#define BHT 128   // h-cols per block
#define BKT 64

__device__ inline void gload_lds16(const void* g, void* lds) {
  __builtin_amdgcn_global_load_lds(
      (const __attribute__((address_space(1))) unsigned int*)g,
      (__attribute__((address_space(3))) unsigned int*)lds,
      16, 0, 0);
}

__device__ inline unsigned short bf16_rne(float f) {
  unsigned int u = __float_as_uint(f);
  unsigned int r = (u + 0x7FFFu + ((u >> 16) & 1u)) >> 16;
  return (unsigned short)r;
}

__device__ inline uint2 pack4_bf16(const float* p) {
  uint2 hv;
  hv.x = (unsigned)bf16_rne(p[0]) | ((unsigned)bf16_rne(p[1]) << 16);
  hv.y = (unsigned)bf16_rne(p[2]) | ((unsigned)bf16_rne(p[3]) << 16);
  return hv;
}

// Merged prep: blocks [0,16384) convert x -> xb; blocks [16384,16896) W -> Wc.
__global__ __launch_bounds__(256) void prep_all(
    const float* __restrict__ x, const float* __restrict__ Wz,
    const float* __restrict__ Wh, unsigned short* __restrict__ xb,
    unsigned short* __restrict__ Wc) {
  int bid = blockIdx.x;
  if (bid < 16384) {
    size_t i = (size_t)bid * 256 + threadIdx.x;
    float4 w = *(const float4*)(x + i * 4);
    *(uint2*)(xb + i * 4) = pack4_bf16((const float*)&w);
  } else {
    int j = (bid - 16384) * 256 + threadIdx.x;
    const float* src = (j < 65536) ? (Wz + (size_t)j * 4)
                                   : (Wh + (size_t)(j - 65536) * 4);
    float4 w = *(const float4*)src;
    *(uint2*)(Wc + (size_t)j * 4) = pack4_bf16((const float*)&w);
  }
}

// W-only prep (fallback when ws too small for xb)
__global__ __launch_bounds__(256) void prep_w(
    const float* __restrict__ Wz, const float* __restrict__ Wh,
    unsigned short* __restrict__ Wc) {
  int j = blockIdx.x * 256 + threadIdx.x;
  const float* src = (j < 65536) ? (Wz + (size_t)j * 4)
                                 : (Wh + (size_t)(j - 65536) * 4);
  float4 w = *(const float4*)src;
  *(uint2*)(Wc + (size_t)j * 4) = pack4_bf16((const float*)&w);
}

// Fused GEMM: per block computes k = x@Wz^T+bz AND ph = x@Wh^T+bh for a
// 128-row x 128-h tile, applies gates in-register, stores packed
// (half(a)|half(v)<<16) to av, and writes per-32-row-chunk scan aggregates
// (A=prod a, H=chunk-local scan end) to aggA/aggH -- scan_chunk eliminated.
// LDS: T2 XOR swizzle, linear dest + pre-swizzled global source (rule #21).
template <int XB>
__global__ __launch_bounds__(256, 2) void gemm_fused(
    const float* __restrict__ x, const unsigned short* __restrict__ xb,
    const unsigned short* __restrict__ Wc,
    const float* __restrict__ bz, const float* __restrict__ bh,
    unsigned int* __restrict__ av,
    float* __restrict__ aggA, float* __restrict__ aggH) {
  __shared__ __align__(16) char smem[49152];
  unsigned short* Abf = (unsigned short*)smem;             // [128*64] 16KB
  unsigned short* Bzf = (unsigned short*)(smem + 16384);   // Wz panel 16KB
  unsigned short* Bhf = (unsigned short*)(smem + 32768);   // Wh panel 16KB
  float* AsL = (float*)smem;                               // [32][128] alias
  float* HsL = (float*)(smem + 16384);                     // [32][128] alias

  const int tid = threadIdx.x;
  const int lane = tid & 63, wid = tid >> 6;
  // XCD-aware bijective swizzle (1024 % 8 == 0): each XCD gets 32 bm x 4 hn
  int swz = (blockIdx.x & 7) * 128 + (blockIdx.x >> 3);
  const int bm = swz >> 2, hn = swz & 3;
  const int row0 = bm * BMT, h0 = hn * BHT;

  const int wr = (wid >> 1) * 64, hc = (wid & 1) * 64;  // wave sub-tile
  const int fr = lane & 15, kg = lane >> 4;

  // gload: wave covers 8 rows x 64 cols per issue; pre-swizzled source slot
  const int r8 = lane >> 3;
  const int c8 = ((lane & 7) ^ r8) * 8;
  // fragment-read swizzled slots
  const int fr7 = lane & 7;
  const int sk0 = (kg ^ fr7) * 8;
  const int sk1 = ((kg + 4) ^ fr7) * 8;

  f32x4 ak[4][4], ap[4][4];
#pragma unroll
  for (int i = 0; i < 4; ++i)
#pragma unroll
    for (int j = 0; j < 4; ++j) { ak[i][j] = (f32x4)0.f; ap[i][j] = (f32x4)0.f; }

  for (int k0 = 0; k0 < Dd; k0 += BKT) {
    if constexpr (XB) {
      __syncthreads();  // previous iter's fragment reads complete
#pragma unroll
      for (int i = 0; i < 4; ++i) {
        int rw = wid * 32 + i * 8;   // wave-uniform stripe base
        gload_lds16(xb + (size_t)(row0 + rw + r8) * Dd + k0 + c8, &Abf[rw * BKT]);
        gload_lds16(Wc + (size_t)(h0 + rw + r8) * Dd + k0 + c8, &Bzf[rw * BKT]);
        gload_lds16(Wc + (size_t)(512 + h0 + rw + r8) * Dd + k0 + c8, &Bhf[rw * BKT]);
      }
      __syncthreads();  // drains vmcnt before barrier
    } else {
      float4 avx[8];
#pragma unroll
      for (int i = 0; i < 8; ++i) {
        int f = i * 256 + tid;
        avx[i] = *(const float4*)(x + (size_t)(row0 + (f >> 4)) * Dd + k0 + (f & 15) * 4);
      }
      __syncthreads();
#pragma unroll
      for (int i = 0; i < 4; ++i) {
        int rw = wid * 32 + i * 8;
        gload_lds16(Wc + (size_t)(h0 + rw + r8) * Dd + k0 + c8, &Bzf[rw * BKT]);
        gload_lds16(Wc + (size_t)(512 + h0 + rw + r8) * Dd + k0 + c8, &Bhf[rw * BKT]);
      }
#pragma unroll
      for (int i = 0; i < 8; ++i) {
        int f = i * 256 + tid;
        int r = f >> 4;
        uint2 hv = pack4_bf16((const float*)&avx[i]);
        int soff = ((((f & 15) >> 1) ^ (r & 7)) * 8) + (f & 1) * 4;
        *(uint2*)&Abf[r * BKT + soff] = hv;
      }
      __syncthreads();
    }

#pragma unroll
    for (int ks = 0; ks < 2; ++ks) {
      const int sk = ks ? sk1 : sk0;
      short8 fa[4], fz[4], fh[4];
#pragma unroll
      for (int mi = 0; mi < 4; ++mi)
        fa[mi] = *(const short8*)&Abf[(wr + mi * 16 + fr) * BKT + sk];
#pragma unroll
      for (int ni = 0; ni < 4; ++ni) {
        fz[ni] = *(const short8*)&Bzf[(hc + ni * 16 + fr) * BKT + sk];
        fh[ni] = *(const short8*)&Bhf[(hc + ni * 16 + fr) * BKT + sk];
      }
#pragma unroll
      for (int mi = 0; mi < 4; ++mi)
#pragma unroll
        for (int ni = 0; ni < 4; ++ni) {
          ak[mi][ni] = __builtin_amdgcn_mfma_f32_16x16x32_bf16(fa[mi], fz[ni], ak[mi][ni], 0, 0, 0);
          ap[mi][ni] = __builtin_amdgcn_mfma_f32_16x16x32_bf16(fa[mi], fh[ni], ap[mi][ni], 0, 0, 0);
        }
    }
  }

  // ---- Fused epilogue ----
  __syncthreads();   // all LDS staging reads done; smem reusable for As/Hs

  // C/D layout: col=lane&15 (fr), row=(lane>>4)*4+j (kg,j)
#pragma unroll
  for (int ni = 0; ni < 4; ++ni) {
    int colG = h0 + hc + ni * 16 + fr;
    float bzv = bz[colG];
    float bhv = bh[colG];
#pragma unroll
    for (int mi = 0; mi < 4; ++mi) {
      float A4 = 1.f, H4 = 0.f;
#pragma unroll
      for (int j = 0; j < 4; ++j) {
        float kv = ak[mi][ni][j] + bzv;
        float pv = ap[mi][ni][j] + bhv;
        float a = 1.f / (1.f + __expf(kv));           // sigmoid(-k)
        float z = 1.f - a;
        float g = (pv >= 0.f) ? (pv + 0.5f) : 1.f / (1.f + __expf(-pv));
        float v = z * g;
        int row = row0 + wr + mi * 16 + kg * 4 + j;
        unsigned int u = (unsigned int)__half_as_ushort(__float2half_rn(a)) |
                         ((unsigned int)__half_as_ushort(__float2half_rn(v)) << 16);
        av[(size_t)row * Hh + colG] = u;
        H4 = fmaf(a, H4, v);     // 4-row segment scan
        A4 *= a;
      }
      // segment (4 rows) -> LDS: srow = local_row/4
      int srow = (wr >> 2) + mi * 4 + kg;
      int cl = hc + ni * 16 + fr;
      AsL[srow * BHT + cl] = A4;
      HsL[srow * BHT + cl] = H4;
    }
  }
  __syncthreads();

  // fold 8 segments -> 1 chunk (32 rows); 4 chunks x 128 cols = 512 outputs
  const int b = row0 >> 12;
  const int cbase = (row0 & 4095) >> 5;   // first global chunk of this block
#pragma unroll
  for (int p0 = 0; p0 < 2; ++p0) {
    int p = p0 * 256 + tid;
    int chunk = p >> 7, cl = p & 127;
    float A = 1.f, H = 0.f;
#pragma unroll
    for (int s = 0; s < 8; ++s) {
      int srow = chunk * 8 + s;
      float As = AsL[srow * BHT + cl];
      float Hs = HsL[srow * BHT + cl];
      H = fmaf(As, H, Hs);
      A *= As;
    }
    size_t idx = ((size_t)b * CHUNKS + cbase + chunk) * Hh + h0 + cl;
    aggA[idx] = A;
    aggH[idx] = H;
  }
}

// Kogge-Stone scan over chunk aggregates (affine composition).
__global__ __launch_bounds__(256) void scan_carry_ks(
    const float* __restrict__ aggA, const float* __restrict__ aggH,
    const float* __restrict__ h0, float* __restrict__ carry) {
  __shared__ float As[256], Hs[256];
  const int tid = threadIdx.x;
  const int c = tid & 127;
  const int gch = blockIdx.x * 2 + (tid >> 7);   // 0..B*H-1
  const int b = gch >> 9, h = gch & 511;
  size_t base = (size_t)b * CHUNKS * Hh + h;
  float A = aggA[base + (size_t)c * Hh];
  float H = aggH[base + (size_t)c * Hh];
  As[tid] = A; Hs[tid] = H;
  __syncthreads();
#pragma unroll
  for (int s = 1; s < 128; s <<= 1) {
    float Al = 1.f, Hl = 0.f;
    const bool act = (c >= s);
    if (act) { Al = As[tid - s]; Hl = Hs[tid - s]; }
    __syncthreads();
    if (act) {
      H = fmaf(A, Hl, H);
      A = A * Al;
      As[tid] = A; Hs[tid] = H;
    }
    __syncthreads();
  }
  float hv = h0[(size_t)b * Hh + h];
  float g0 = (hv >= 0.f) ? (hv + 0.5f) : 1.f / (1.f + __expf(-hv));  // g(h0)
  float cr;
  if (c == 0) cr = g0;
  else cr = fmaf(As[tid - 1], g0, Hs[tid - 1]);
  carry[base + (size_t)c * Hh] = cr;
}

// Apply carry: read packed (a,v), write final h (fp32) to d_out.
__global__ __launch_bounds__(512) void scan_apply_av(
    const unsigned int* __restrict__ av, const float* __restrict__ carry,
    float* __restrict__ out) {
  const int h = threadIdx.x;
  const int bc = blockIdx.x;
  const int b = bc >> 7, c = bc & 127;
  float hp = carry[(size_t)bc * Hh + h];
  size_t base = ((size_t)b * Tt + (size_t)c * CLEN) * Hh + h;
#pragma unroll
  for (int i = 0; i < CLEN; ++i) {
    size_t idx = base + (size_t)i * Hh;
    unsigned int u = av[idx];
    float a = __half2float(__ushort_as_half((unsigned short)(u & 0xFFFFu)));
    float v = __half2float(__ushort_as_half((unsigned short)(u >> 16)));
    hp = fmaf(a, hp, v);
    out[idx] = hp;
  }
}

extern "C" void kernel_launch(void* const* d_in, const int* in_sizes, int n_in,
                              void* d_out, int out_size, void* d_ws, size_t ws_size,
                              hipStream_t stream) {
  const float* x  = (const float*)d_in[0];
  const float* h0 = (const float*)d_in[1];
  const float* Wz = (const float*)d_in[2];
  const float* bz = (const float*)d_in[3];
  const float* Wh = (const float*)d_in[4];
  const float* bh = (const float*)d_in[5];
  float* out = (float*)d_out;

  char* w = (char*)d_ws;
  unsigned int* avb    = (unsigned int*)w;                 // 64 MB packed (a,v)
  unsigned short* Wc   = (unsigned short*)(w + 67108864);  // 1 MB
  float* aggA          = (float*)(w + 68157440);           // 2 MB
  float* aggH          = (float*)(w + 70254592);           // 2 MB
  float* carry         = (float*)(w + 72351744);           // 2 MB (end 74448896)
  unsigned short* xb   = (unsigned short*)(w + 74448896);  // 32 MB (end 108003328)
  const bool useXB = ws_size >= 108003328ull;

  const int grid = (Mm / BMT) * (Hh / BHT);  // 256 * 4 = 1024
  if (useXB) {
    prep_all<<<16896, 256, 0, stream>>>(x, Wz, Wh, xb, Wc);
    gemm_fused<1><<<grid, 256, 0, stream>>>(x, xb, Wc, bz, bh, avb, aggA, aggH);
  } else {
    prep_w<<<512, 256, 0, stream>>>(Wz, Wh, Wc);
    gemm_fused<0><<<grid, 256, 0, stream>>>(x, xb, Wc, bz, bh, avb, aggA, aggH);
  }
  scan_carry_ks<<<(Bb * Hh) / 2, 256, 0, stream>>>(aggA, aggH, h0, carry);
  scan_apply_av<<<Bb * CHUNKS, 512, 0, stream>>>(avb, carry, out);
}